// Round 1
// baseline (4033.775 us; speedup 1.0000x reference)
//
#include <hip/hip_runtime.h>
#include <hip/hip_bf16.h>
#include <math.h>

#define KS 3
#define C_IN 64
#define F_OUT 128
#define NPOS 9
#define HH 128
#define WW 128
#define NBATCH 16

// Kernel 1: AW_flat[L] = topk-mask * sign(kern_flat[L]); all tensors index-aligned on L.
// One thread per (f2,c2) pair -> owns L in [t*9, t*9+9).
__global__ void compute_aw(const float* __restrict__ kern,
                           const float* __restrict__ D,
                           const float* __restrict__ gu,
                           float* __restrict__ AW) {
  int t = blockIdx.x * blockDim.x + threadIdx.x;
  if (t >= F_OUT * C_IN) return;
  int base = t * NPOS;
  float pert[NPOS];
#pragma unroll
  for (int n = 0; n < NPOS; ++n) {
    float u = gu[base + n];
    float g = -0.001f * logf(-logf(u + 1e-20f) + 1e-20f);
    pert[n] = D[base + n] + g;
  }
  // top-4 set of 9 (ties ~impossible with continuous random data; strict > picks
  // lowest index first, matching lax.top_k)
  unsigned mask = 0;
#pragma unroll
  for (int k = 0; k < 4; ++k) {
    int best = 0; float bv = -INFINITY;
#pragma unroll
    for (int n = 0; n < NPOS; ++n) {
      bool taken = (mask >> n) & 1;
      if (!taken && pert[n] > bv) { bv = pert[n]; best = n; }
    }
    mask |= (1u << best);
  }
#pragma unroll
  for (int n = 0; n < NPOS; ++n) {
    float kv = kern[base + n];
    float s = (kv > 0.f) ? 1.f : ((kv < 0.f) ? -1.f : 0.f);  // jnp.sign
    AW[base + n] = ((mask >> n) & 1) ? s : 0.f;
  }
}

// Kernel 2: direct 3x3 SAME conv, NHWC, one output element per thread.
// f fastest in tid -> AW loads coalesced across the wave; x loads wave-uniform
// (broadcast), vectorized float4 over channels.
__global__ void conv_direct(const float* __restrict__ x,
                            const float* __restrict__ AW,
                            const float* __restrict__ bias,
                            float* __restrict__ out) {
  long long idx = (long long)blockIdx.x * blockDim.x + threadIdx.x;
  int f = (int)(idx & (F_OUT - 1));
  long long rest = idx >> 7;
  int w = (int)(rest & (WW - 1)); rest >>= 7;
  int h = (int)(rest & (HH - 1)); rest >>= 7;
  int n = (int)rest;

  float acc = bias[f];
#pragma unroll
  for (int i = 0; i < KS; ++i) {
    int hh = h + i - 1;
    if ((unsigned)hh >= (unsigned)HH) continue;
#pragma unroll
    for (int j = 0; j < KS; ++j) {
      int wq = w + j - 1;
      if ((unsigned)wq >= (unsigned)WW) continue;
      const float* xp = x + (((long long)n * HH + hh) * WW + wq) * C_IN;
      const float* wp = AW + (size_t)(i * KS + j) * C_IN * F_OUT + f;
#pragma unroll
      for (int c4 = 0; c4 < C_IN; c4 += 4) {
        float4 xv = *reinterpret_cast<const float4*>(xp + c4);
        acc = fmaf(xv.x, wp[(c4 + 0) * F_OUT], acc);
        acc = fmaf(xv.y, wp[(c4 + 1) * F_OUT], acc);
        acc = fmaf(xv.z, wp[(c4 + 2) * F_OUT], acc);
        acc = fmaf(xv.w, wp[(c4 + 3) * F_OUT], acc);
      }
    }
  }
  out[idx] = fmaxf(acc, 0.f);
}

extern "C" void kernel_launch(void* const* d_in, const int* in_sizes, int n_in,
                              void* d_out, int out_size, void* d_ws, size_t ws_size,
                              hipStream_t stream) {
  const float* x    = (const float*)d_in[0];  // (16,128,128,64)
  const float* kern = (const float*)d_in[1];  // (3,3,64,128)
  const float* bias = (const float*)d_in[2];  // (128,)
  const float* D    = (const float*)d_in[3];  // (3,3,64,128)
  const float* gu   = (const float*)d_in[4];  // (1,128,64,9)

  float* AW = (float*)d_ws;  // 73728 floats = 288 KiB scratch

  compute_aw<<<(F_OUT * C_IN + 255) / 256, 256, 0, stream>>>(kern, D, gu, AW);

  long long total = (long long)NBATCH * HH * WW * F_OUT;  // 33,554,432
  conv_direct<<<(int)(total / 256), 256, 0, stream>>>(x, AW, bias, (float*)d_out);
}

// Round 2
// 183.798 us; speedup vs baseline: 21.9468x; 21.9468x over previous
//
#include <hip/hip_runtime.h>
#include <hip/hip_bf16.h>
#include <math.h>

#define KS 3
#define C_IN 64
#define F_OUT 128
#define NPOS 9
#define HH 128
#define WWID 128
#define NB 16

typedef __attribute__((ext_vector_type(8))) short bf16x8;
typedef __attribute__((ext_vector_type(4))) float f32x4;

__device__ __forceinline__ unsigned short f2bf(float f) {
  union { float f; unsigned u; } v; v.f = f;
  unsigned u = v.u;
  unsigned r = (u + 0x7FFFu + ((u >> 16) & 1u)) >> 16;  // RNE
  return (unsigned short)r;
}

// ---- Kernel 1: AWt[p][f][c] (bf16) = topk-mask(L) * sign(kern_flat[L]),
// L = ((p)*64+c)*128+f. One thread per (f2,c2) pair; t = f2*64+c2 owns L in
// [t*9, t*9+9) (D/gumbel/kern/A are all raw-reshape index-aligned on L).
__global__ void compute_aw(const float* __restrict__ kern,
                           const float* __restrict__ D,
                           const float* __restrict__ gu,
                           unsigned short* __restrict__ AWt) {
  int t = blockIdx.x * blockDim.x + threadIdx.x;
  if (t >= F_OUT * C_IN) return;
  int base = t * NPOS;
  float pert[NPOS];
#pragma unroll
  for (int n = 0; n < NPOS; ++n) {
    float u = gu[base + n];
    float g = -0.001f * logf(-logf(u + 1e-20f) + 1e-20f);
    pert[n] = D[base + n] + g;
  }
  unsigned mask = 0;
#pragma unroll
  for (int k = 0; k < 4; ++k) {
    int best = 0; float bv = -INFINITY;
#pragma unroll
    for (int n = 0; n < NPOS; ++n) {
      bool taken = (mask >> n) & 1;
      if (!taken && pert[n] > bv) { bv = pert[n]; best = n; }
    }
    mask |= (1u << best);
  }
#pragma unroll
  for (int n = 0; n < NPOS; ++n) {
    int L = base + n;
    float kv = kern[L];
    float s = (kv > 0.f) ? 1.f : ((kv < 0.f) ? -1.f : 0.f);
    float v = ((mask >> n) & 1) ? s : 0.f;
    int f = L & (F_OUT - 1);
    int r = L >> 7;          // = p*64 + c
    int c = r & (C_IN - 1);
    int p = r >> 6;
    AWt[(p * F_OUT + f) * C_IN + c] = f2bf(v);
  }
}

// ---- Kernel 2: implicit-GEMM conv via MFMA 16x16x32 bf16.
// Block = (n,h) image row: M=128 (w), N=128 (f), K=576 = 9 pos x 64 ch.
// A-tile (3 padded x-rows, bf16, XOR-swizzled) staged in LDS once.
// B (AWt) read from global (L1/L2-resident, 144 KiB total).
__global__ void conv_mfma(const float* __restrict__ x,
                          const short* __restrict__ AWt,
                          const float* __restrict__ bias,
                          float* __restrict__ out) {
  // 3 rows x 130 padded pixels x 64 ch bf16; row pitch 128 B.
  __shared__ __align__(16) char xs[3 * 130 * 128];

  int bid = blockIdx.x;
  int wg = (bid & 7) * 256 + (bid >> 3);   // XCD-contiguous (2048 % 8 == 0)
  int n = wg >> 7;
  int h = wg & (HH - 1);

  // ---- stage x rows h-1..h+1 into LDS as bf16, zero-padded, swizzled.
  // item = (i, q, g): q in [0,130) padded pixel, g = 4-channel group.
  for (int it = threadIdx.x; it < 3 * 130 * 16; it += 256) {
    int i = it / (130 * 16);
    int rem = it - i * (130 * 16);
    int q = rem >> 4;
    int g = rem & 15;
    int c = g * 4;
    int hh = h + i - 1;
    int wq = q - 1;
    ushort4 v4 = make_ushort4(0, 0, 0, 0);
    if ((unsigned)hh < (unsigned)HH && (unsigned)wq < (unsigned)WWID) {
      const float4 xv = *reinterpret_cast<const float4*>(
          x + (((long long)n * HH + hh) * WWID + wq) * C_IN + c);
      v4.x = f2bf(xv.x); v4.y = f2bf(xv.y); v4.z = f2bf(xv.z); v4.w = f2bf(xv.w);
    }
    int cb = c * 2;
    int off = (i * 130 + q) * 128 + (cb ^ ((q & 7) << 4));
    *reinterpret_cast<ushort4*>(xs + off) = v4;
  }
  __syncthreads();

  int lane = threadIdx.x & 63;
  int wave = threadIdx.x >> 6;
  int m0 = wave * 32;          // wave's w-range: [m0, m0+32)
  int lr = lane & 15;
  int lg = lane >> 4;

  f32x4 acc[2][8] = {};

  // K-frags: kk in [0,18): p = kk>>1 (conv position), ch = kk&1 (channel half).
  // A: lane holds row w=(m-tile)+lr, k = lg*8 + j (8 consecutive ch).
  // B: lane holds col f=(n-frag)+lr, same k  ->  AWt[p][f][c0..c0+7].
#pragma unroll 1
  for (int kk = 0; kk < 18; ++kk) {
    int p = kk >> 1, ch = kk & 1;
    int i = p / 3, j = p % 3;
    bf16x8 b[8];
#pragma unroll
    for (int nf = 0; nf < 8; ++nf)
      b[nf] = *reinterpret_cast<const bf16x8*>(
          AWt + ((p * F_OUT + nf * 16 + lr) * C_IN + ch * 32 + lg * 8));
#pragma unroll
    for (int mf = 0; mf < 2; ++mf) {
      int q = m0 + mf * 16 + lr + j;         // padded pixel index (w + j)
      int cb = ch * 64 + lg * 16;            // byte offset of 8-ch group
      int off = (i * 130 + q) * 128 + (cb ^ ((q & 7) << 4));
      bf16x8 a = *reinterpret_cast<const bf16x8*>(xs + off);
#pragma unroll
      for (int nf = 0; nf < 8; ++nf)
        acc[mf][nf] = __builtin_amdgcn_mfma_f32_16x16x32_bf16(a, b[nf], acc[mf][nf], 0, 0, 0);
    }
  }

  // ---- epilogue: D frag lane mapping col=lr, row=lg*4+r.
  long long obase = (((long long)n * HH + h) * WWID) * F_OUT;
#pragma unroll
  for (int mf = 0; mf < 2; ++mf) {
#pragma unroll
    for (int nf = 0; nf < 8; ++nf) {
      int f = nf * 16 + lr;
      float bb = bias[f];
#pragma unroll
      for (int r = 0; r < 4; ++r) {
        int w = m0 + mf * 16 + lg * 4 + r;
        float v = acc[mf][nf][r] + bb;
        out[obase + (long long)w * F_OUT + f] = fmaxf(v, 0.f);
      }
    }
  }
}

extern "C" void kernel_launch(void* const* d_in, const int* in_sizes, int n_in,
                              void* d_out, int out_size, void* d_ws, size_t ws_size,
                              hipStream_t stream) {
  const float* x    = (const float*)d_in[0];  // (16,128,128,64)
  const float* kern = (const float*)d_in[1];  // (3,3,64,128)
  const float* bias = (const float*)d_in[2];  // (128,)
  const float* D    = (const float*)d_in[3];  // (3,3,64,128)
  const float* gu   = (const float*)d_in[4];  // (1,128,64,9)

  unsigned short* AWt = (unsigned short*)d_ws;  // 9*128*64 bf16 = 144 KiB

  compute_aw<<<(F_OUT * C_IN + 255) / 256, 256, 0, stream>>>(kern, D, gu, AWt);

  conv_mfma<<<NB * HH, 256, 0, stream>>>(x, (const short*)AWt, bias, (float*)d_out);
}